// Round 9
// baseline (260.363 us; speedup 1.0000x reference)
//
#include <hip/hip_runtime.h>
#include <hip/hip_bf16.h>
#include <math.h>

// Problem constants
#define Bsz   256
#define INDIM 2048
#define Dd    128
#define Kq    65536
#define NH    32
#define S1n   16
#define S2n   16
#define ROWLEN (1 + Kq + S1n + S2n)   // 65569
#define CAP   2048                     // candidate cap (collect / select)
#define CAPL  6144                     // select repair-scan LDS capacity (R2-proven)
#define NCHUNK 8                       // split-K chunks of 256 for encoder GEMM
#define CK    256                      // K per chunk
#define GBLK  512                      // gemmB grid (2 tiles of 64 cols each)

typedef __attribute__((ext_vector_type(8))) short short8;
typedef __attribute__((ext_vector_type(4))) float f32x4;
typedef float float4a __attribute__((ext_vector_type(4), aligned(4)));
union U16x8 { uint4 u4; short8 s8; };

static __device__ inline unsigned short bf16rne(float f) {
    unsigned u = __float_as_uint(f);
    unsigned r = (u + 0x7FFFu + ((u >> 16) & 1u)) >> 16;
    return (unsigned short)r;
}
static __device__ inline unsigned fkey(float f) {   // monotone uint key
    unsigned u = __float_as_uint(f);
    return (u & 0x80000000u) ? ~u : (u | 0x80000000u);
}
static __device__ inline float funkey(unsigned key) {
    unsigned u = (key & 0x80000000u) ? (key & 0x7FFFFFFFu) : ~key;
    return __uint_as_float(u);
}

// ---------------- Kernel A1: fp64 split-K encoder GEMM (a0 fused inline) -------
// k-path computes Wk_new = 0.999f*Wk + 0.001f*Wq inline with the EXACT fp32
// arithmetic the old a0 kernel used (bit-identical), removing one launch and
// the wknew global round-trip.
__global__ __launch_bounds__(256) void moco_a1(const float* __restrict__ q,
                                               const float* __restrict__ k,
                                               const float* __restrict__ Wq,
                                               const float* __restrict__ Wk,
                                               double* __restrict__ partq,
                                               float* __restrict__ partk) {
    int kc    = blockIdx.x;        // 0..NCHUNK-1
    int grp   = blockIdx.y;        // 0..127, 4 rows each
    int vrow0 = grp * 4;
    bool isK  = (vrow0 >= Bsz);
    const float* inp = isK ? k : q;
    int row0 = isK ? (vrow0 - Bsz) : vrow0;
    int i0 = kc * CK;

    __shared__ float s_in[4 * CK];
    #pragma unroll
    for (int it = 0; it < 4; ++it) {
        int idx = threadIdx.x + it * 256;
        int rr = idx >> 8, ii = idx & (CK - 1);
        s_in[idx] = inp[(size_t)(row0 + rr) * INDIM + i0 + ii];
    }
    __syncthreads();

    int ct = threadIdx.x & 63;     // one wave == one row -> srow reads broadcast
    int rt = threadIdx.x >> 6;
    int d0 = ct * 2;
    const float* baseWq = Wq + (size_t)i0 * Dd + d0;
    const float* baseWk = Wk + (size_t)i0 * Dd + d0;
    const float* srow = &s_in[rt * CK];

    double acc0 = 0, acc1 = 0;
    int prow = row0 + rt;
    if (isK) {
        #pragma unroll 16
        for (int i = 0; i < CK; ++i) {
            float2 wk = *(const float2*)(baseWk + (size_t)i * Dd);
            float2 wq = *(const float2*)(baseWq + (size_t)i * Dd);
            float wx = 0.999f * wk.x + 0.001f * wq.x;   // == old a0, bit-identical
            float wy = 0.999f * wk.y + 0.001f * wq.y;
            double a = (double)srow[i];
            acc0 += a * (double)wx;
            acc1 += a * (double)wy;
        }
        float2 r; r.x = (float)acc0; r.y = (float)acc1;
        *(float2*)(partk + ((size_t)kc * 256 + prow) * Dd + d0) = r;
    } else {
        #pragma unroll 16
        for (int i = 0; i < CK; ++i) {
            float2 w = *(const float2*)(baseWq + (size_t)i * Dd);
            double a = (double)srow[i];
            acc0 += a * (double)w.x;
            acc1 += a * (double)w.y;
        }
        double2 r; r.x = acc0; r.y = acc1;
        *(double2*)(partq + ((size_t)kc * 256 + prow) * Dd + d0) = r;
    }
}

// ---------------- Kernel A2: combine, normalize (f64), pos logit, labels, bf16 out_q ----
__global__ __launch_bounds__(128) void moco_a2(const double* __restrict__ partq,
                                               const float* __restrict__ partk,
                                               double* __restrict__ outq64,
                                               unsigned short* __restrict__ outq16,
                                               int* __restrict__ ccnt,
                                               float* __restrict__ out) {
    int b = blockIdx.x, d = threadIdx.x;
    if (d == 0) ccnt[b] = 0;                     // init for moco_collect
    double sq = 0, sk = 0;
    #pragma unroll
    for (int kc = 0; kc < NCHUNK; ++kc) {
        sq += partq[((size_t)kc * 256 + b) * Dd + d];
        sk += (double)partk[((size_t)kc * 256 + b) * Dd + d];
    }
    __shared__ double red[128];
    red[d] = sq * sq; __syncthreads();
    for (int s = 64; s > 0; s >>= 1) { if (d < s) red[d] += red[d + s]; __syncthreads(); }
    double nq = sqrt(red[0]); __syncthreads();
    red[d] = sk * sk; __syncthreads();
    for (int s = 64; s > 0; s >>= 1) { if (d < s) red[d] += red[d + s]; __syncthreads(); }
    double nk = sqrt(red[0]); __syncthreads();

    double oq = sq / fmax(nq, 1e-12);
    double ok = sk / fmax(nk, 1e-12);
    outq64[(size_t)b * Dd + d] = oq;
    outq16[(size_t)b * Dd + d] = bf16rne((float)oq);

    red[d] = oq * ok; __syncthreads();
    for (int s = 64; s > 0; s >>= 1) { if (d < s) red[d] += red[d + s]; __syncthreads(); }
    if (d == 0) {
        out[(size_t)b * ROWLEN] = (float)(red[0] / 0.07);
        ((int*)out)[(size_t)Bsz * ROWLEN + b] = 0;   // labels
    }
}

// ---------------- Kernel B: bf16 MFMA GEMM + per-row max -> out[:,1:1+K] -------
// rmaxpart now TRANSPOSED: [row][block] so downstream reads each row's 512
// block-maxima as one contiguous coalesced 2KB stretch (replaces the rowmax
// kernel). The scatter store here is fire-and-forget.
#define GB_BN 64
__global__ __launch_bounds__(256) void moco_gemmB(const unsigned short* __restrict__ outq16,
                                                  const float* __restrict__ Q,
                                                  unsigned* __restrict__ rmaxpartT,
                                                  float* __restrict__ out) {
    int tid = threadIdx.x;
    int w = tid >> 6, lane = tid & 63;
    int quad = lane >> 4, l16 = lane & 15;
    int bn_base = blockIdx.x * (2 * GB_BN);

    __shared__ unsigned short q_lds[64 * 136];   // stride 136 bf16
    __shared__ unsigned s_rmax[256];
    s_rmax[tid] = 0;

    // A fragments from global bf16 (L2-hot 64 KB), reused across both tiles
    short8 afr[4][4];
    #pragma unroll
    for (int i = 0; i < 4; ++i)
        #pragma unroll
        for (int kc = 0; kc < 4; ++kc) {
            U16x8 u;
            u.u4 = *(const uint4*)(outq16 + (size_t)(w * 64 + i * 16 + l16) * Dd + kc * 32 + quad * 8);
            afr[i][kc] = u.s8;
        }

    // prefetch tile 0 queue rows into registers
    int r0 = tid >> 4, kb = tid & 15;            // 16 rows x 16 col-chunks
    float4 pre[8];
    {
        const float* qb = Q + (size_t)bn_base * Dd + (size_t)kb * 8;
        #pragma unroll
        for (int it = 0; it < 4; ++it) {
            const float4* g = (const float4*)(qb + (size_t)(r0 + it * 16) * Dd);
            pre[2 * it]     = g[0];
            pre[2 * it + 1] = g[1];
        }
    }

    const float invT = (float)(1.0 / 0.07);

    #pragma unroll
    for (int tt = 0; tt < 2; ++tt) {
        int bn0 = bn_base + tt * GB_BN;

        // convert prefetched regs -> LDS (fp32 -> bf16 RNE)
        #pragma unroll
        for (int it = 0; it < 4; ++it) {
            float4 f0 = pre[2 * it], f1 = pre[2 * it + 1];
            uint4 pk;
            pk.x = ((unsigned)bf16rne(f0.y) << 16) | bf16rne(f0.x);
            pk.y = ((unsigned)bf16rne(f0.w) << 16) | bf16rne(f0.z);
            pk.z = ((unsigned)bf16rne(f1.y) << 16) | bf16rne(f1.x);
            pk.w = ((unsigned)bf16rne(f1.w) << 16) | bf16rne(f1.z);
            *(uint4*)&q_lds[(r0 + it * 16) * 136 + kb * 8] = pk;
        }
        __syncthreads();

        // issue tile-1 loads now; they complete under tile-0 MFMA + stores
        if (tt == 0) {
            const float* qb2 = Q + (size_t)(bn_base + GB_BN) * Dd + (size_t)kb * 8;
            #pragma unroll
            for (int it = 0; it < 4; ++it) {
                const float4* g = (const float4*)(qb2 + (size_t)(r0 + it * 16) * Dd);
                pre[2 * it]     = g[0];
                pre[2 * it + 1] = g[1];
            }
        }

        f32x4 acc[4][4];
        #pragma unroll
        for (int i = 0; i < 4; ++i)
            #pragma unroll
            for (int j = 0; j < 4; ++j)
                acc[i][j] = (f32x4){0.f, 0.f, 0.f, 0.f};

        #pragma unroll
        for (int kc = 0; kc < 4; ++kc) {
            short8 bfr[4];
            #pragma unroll
            for (int j = 0; j < 4; ++j)
                bfr[j] = *(const short8*)&q_lds[(j * 16 + l16) * 136 + kc * 32 + quad * 8];
            #pragma unroll
            for (int i = 0; i < 4; ++i)
                #pragma unroll
                for (int j = 0; j < 4; ++j)
                    acc[i][j] = __builtin_amdgcn_mfma_f32_16x16x32_bf16(afr[i][kc], bfr[j], acc[i][j], 0, 0, 0);
        }

        #pragma unroll
        for (int i = 0; i < 4; ++i) {
            int rbase = w * 64 + i * 16 + quad * 4;
            #pragma unroll
            for (int reg = 0; reg < 4; ++reg) {
                size_t ro = (size_t)(rbase + reg) * ROWLEN + 1 + bn0;
                float v0 = acc[i][0][reg] * invT;
                float v1 = acc[i][1][reg] * invT;
                float v2 = acc[i][2][reg] * invT;
                float v3 = acc[i][3][reg] * invT;
                out[ro + l16]      = v0;
                out[ro + 16 + l16] = v1;
                out[ro + 32 + l16] = v2;
                out[ro + 48 + l16] = v3;
                float m = fmaxf(fmaxf(v0, v1), fmaxf(v2, v3));
                atomicMax(&s_rmax[rbase + reg], fkey(m));
            }
        }
        __syncthreads();   // q_lds + s_rmax complete before next tile / final store
    }

    // transposed scatter: row-major layout for coalesced downstream reads
    rmaxpartT[(size_t)tid * GBLK + blockIdx.x] = s_rmax[tid];
}

// ---------------- Kernel C: candidate collection, LDS-staged (R8-validated) ----
// vmax via contiguous 2KB read of this row's 512 block-maxima + LDS tree.
__global__ __launch_bounds__(512) void moco_collect(const float* __restrict__ out,
                                                    const unsigned* __restrict__ rmaxpartT,
                                                    int* __restrict__ cand,
                                                    int* __restrict__ ccnt) {
    int row = blockIdx.y, chunk = blockIdx.x;
    int t = threadIdx.x;
    __shared__ int s_li[2048];
    __shared__ unsigned s_mk[512];
    __shared__ int s_cnt, s_base;
    if (t == 0) s_cnt = 0;
    s_mk[t] = rmaxpartT[(size_t)row * GBLK + t];   // coalesced
    __syncthreads();
    for (int s = 256; s > 0; s >>= 1) {
        if (t < s) { unsigned a = s_mk[t], b = s_mk[t + s]; s_mk[t] = a > b ? a : b; }
        __syncthreads();
    }
    float vmax = funkey(s_mk[0]);
    float thresh = vmax - 2.0f;

    const float4a* p4 = (const float4a*)(out + (size_t)row * ROWLEN + 1);
    int base = chunk * 4096 + t;                 // float4 index, stride 512
    float4a v0 = p4[base];
    float4a v1 = p4[base + 512];
    float4a v2 = p4[base + 1024];
    float4a v3 = p4[base + 1536];
    float4a v4 = p4[base + 2048];
    float4a v5 = p4[base + 2560];
    float4a v6 = p4[base + 3072];
    float4a v7 = p4[base + 3584];

#define CCHK(vv, ii)                                                                       \
    {                                                                                      \
        _Pragma("unroll")                                                                  \
        for (int e = 0; e < 4; ++e) {                                                      \
            if (vv[e] >= thresh) {                                                         \
                int p = atomicAdd(&s_cnt, 1);                                              \
                if (p < 2048) s_li[p] = (base + (ii) * 512) * 4 + e;                       \
            }                                                                              \
        }                                                                                  \
    }
    CCHK(v0, 0) CCHK(v1, 1) CCHK(v2, 2) CCHK(v3, 3)
    CCHK(v4, 4) CCHK(v5, 5) CCHK(v6, 6) CCHK(v7, 7)
#undef CCHK

    __syncthreads();
    if (t == 0) s_base = atomicAdd(&ccnt[row], s_cnt);   // ONE device atomic per block
    __syncthreads();
    int cnt = s_cnt < 2048 ? s_cnt : 2048;
    int b0 = s_base;
    for (int i = t; i < cnt; i += 512) {
        int pos = b0 + i;
        if (pos < CAP) cand[(size_t)row * CAP + pos] = s_li[i];
    }
}

// ---------------- Kernel D: fused prune + fp64 re-rank + mixed logits ----------
// Prune semantics R8-verbatim (fast gather / 6144-cap repair scan / 128-bin
// histogram with 0.25 margin); survivors stay in LDS and feed the f64 re-rank
// directly (no cand write-back, one launch instead of two).
__global__ __launch_bounds__(512) void moco_select(const float* __restrict__ outv,
                                                   const unsigned* __restrict__ rmaxpartT,
                                                   const int* __restrict__ cand,
                                                   const int* __restrict__ ccnt,
                                                   const double* __restrict__ outq64,
                                                   const float* __restrict__ Qm,
                                                   const float* __restrict__ alpha,
                                                   const float* __restrict__ beta,
                                                   const int* __restrict__ i1a,
                                                   const int* __restrict__ i1b,
                                                   const int* __restrict__ i2,
                                                   float* __restrict__ out) {
    int row = blockIdx.x;
    int t = threadIdx.x;
    const float* p = outv + (size_t)row * ROWLEN + 1;
    __shared__ float lv[CAPL];
    __shared__ int   li[CAPL];
    __shared__ double dval[CAP];
    __shared__ int    didx[CAP];
    __shared__ double oq[Dd];
    __shared__ unsigned hist[128];
    __shared__ unsigned s_mk[512];
    __shared__ int s_cnt, s_thr;
    __shared__ int hard[NH];

    for (int i = t; i < Dd; i += 512) oq[i] = outq64[(size_t)row * Dd + i];
    if (t < NH) hard[t] = 0;                     // defensive init
    s_mk[t] = rmaxpartT[(size_t)row * GBLK + t]; // coalesced
    __syncthreads();
    for (int s = 256; s > 0; s >>= 1) {
        if (t < s) { unsigned a = s_mk[t], b = s_mk[t + s]; s_mk[t] = a > b ? a : b; }
        __syncthreads();
    }
    float vmax = funkey(s_mk[0]);

    // ---- prune phase (R8-verbatim semantics) ----
    int n0 = ccnt[row];
    float W = 2.0f;
    int cnt;
    if (n0 >= NH && n0 <= CAP) {
        cnt = n0;
        for (int c = t; c < cnt; c += 512) {
            int idx = cand[(size_t)row * CAP + c] & (Kq - 1);   // defensive mask
            li[c] = idx;
            lv[c] = p[idx];
        }
        __syncthreads();
    } else {
        // repair path: adaptive full scan (cap CAPL=6144)
        const float4a* p4 = (const float4a*)p;
        cnt = 0;
        for (int attempt = 0; attempt < 5; ++attempt) {
            if (t == 0) s_cnt = 0;
            __syncthreads();
            float thresh = vmax - W;
            #pragma unroll 8
            for (int it = 0; it < 32; ++it) {
                int vi = t + it * 512;              // < 16384
                float4a v = p4[vi];
                #pragma unroll
                for (int e = 0; e < 4; ++e) {
                    float f = v[e];
                    if (f >= thresh) {
                        int pos = atomicAdd(&s_cnt, 1);
                        if (pos < CAPL) { lv[pos] = f; li[pos] = vi * 4 + e; }
                    }
                }
            }
            __syncthreads();
            cnt = s_cnt;
            if (cnt >= NH && cnt <= CAPL) break;
            W = (cnt > CAPL) ? W * 0.5f : W * 2.0f;
            __syncthreads();
        }
        if (cnt > CAPL) cnt = CAPL;   // pathological safety
    }

    // fine prune: 128-bin histogram over [vmax-W, vmax], rank-NH bin minus margin
    if (t < 128) hist[t] = 0;
    __syncthreads();
    float lo = vmax - W;
    float scale = 128.0f / W;
    for (int c = t; c < cnt; c += 512) {
        int b = (int)((lv[c] - lo) * scale);
        b = b < 0 ? 0 : (b > 127 ? 127 : b);
        atomicAdd(&hist[b], 1u);
    }
    __syncthreads();
    if (t == 0) {
        unsigned cum = 0; int b = 127;
        for (; b > 0; --b) { cum += hist[b]; if (cum >= NH) break; }
        int mb = (int)(0.25f * scale) + 1;     // 0.25 logit-unit safety margin
        b -= mb; if (b < 0) b = 0;
        long total = 0;
        for (int x = 127; x >= b; --x) total += hist[x];
        while (total > CAP && b < 127) { total -= hist[b]; ++b; }
        s_thr = b;
        s_cnt = 0;
    }
    __syncthreads();
    float thresh2 = lo + (float)s_thr * (W / 128.0f);
    for (int c = t; c < cnt; c += 512) {
        if (lv[c] >= thresh2) {
            int pos = atomicAdd(&s_cnt, 1);
            if (pos < CAP) didx[pos] = li[c];   // survivors straight to LDS
        }
    }
    __syncthreads();
    int n = s_cnt < CAP ? s_cnt : CAP;
    if (n < 1) n = 1;

    // ---- finalize phase (R8-verbatim semantics, stride 512) ----
    for (int c = t; c < n; c += 512) {
        int idx = didx[c];
        const float* qr = Qm + (size_t)idx * Dd;
        double dot = 0;
        #pragma unroll 4
        for (int i = 0; i < Dd; ++i) dot += oq[i] * (double)qr[i];
        dval[c] = dot / 0.07;
    }
    __syncthreads();

    // exact rank (ties -> lower index first, matching lax.top_k)
    for (int c = t; c < n; c += 512) {
        double v = dval[c]; int id = didx[c];
        int r = 0;
        for (int j = 0; j < n; ++j) {
            double vj = dval[j];
            r += (vj > v) || (vj == v && didx[j] < id);
        }
        if (r < NH) hard[r] = id;
    }
    __syncthreads();

    if (t < S1n) {
        double a = (double)alpha[(size_t)row * S1n + t];
        int g1 = hard[i1a[(size_t)row * S1n + t] & (NH - 1)];
        int g2 = hard[i1b[(size_t)row * S1n + t] & (NH - 1)];
        const float* q1 = Qm + (size_t)g1 * Dd;
        const float* q2 = Qm + (size_t)g2 * Dd;
        double nn = 0, qd = 0;
        #pragma unroll 4
        for (int i = 0; i < Dd; ++i) {
            double m = a * (double)q1[i] + (1.0 - a) * (double)q2[i];
            nn += m * m; qd += oq[i] * m;
        }
        double logit = qd / fmax(sqrt(nn), 1e-12) / 0.07;
        out[(size_t)row * ROWLEN + 1 + Kq + t] = (float)logit;
    } else if (t < S1n + S2n) {
        int s = t - S1n;
        double bb = (double)beta[(size_t)row * S2n + s] * 0.5;
        int g = hard[i2[(size_t)row * S2n + s] & (NH - 1)];
        const float* qg = Qm + (size_t)g * Dd;
        double nn = 0, qd = 0;
        #pragma unroll 4
        for (int i = 0; i < Dd; ++i) {
            double m = bb * oq[i] + (1.0 - bb) * (double)qg[i];
            nn += m * m; qd += oq[i] * m;
        }
        double logit = qd / fmax(sqrt(nn), 1e-12) / 0.07;
        out[(size_t)row * ROWLEN + 1 + Kq + S1n + s] = (float)logit;
    }
}

extern "C" void kernel_launch(void* const* d_in, const int* in_sizes, int n_in,
                              void* d_out, int out_size, void* d_ws, size_t ws_size,
                              hipStream_t stream) {
    const float* q     = (const float*)d_in[0];
    const float* k     = (const float*)d_in[1];
    const float* Wq    = (const float*)d_in[2];
    const float* Wk    = (const float*)d_in[3];
    const float* queue = (const float*)d_in[4];
    const float* alpha = (const float*)d_in[5];
    const float* beta  = (const float*)d_in[6];
    const int*   i1a   = (const int*)d_in[7];
    const int*   i1b   = (const int*)d_in[8];
    const int*   i2    = (const int*)d_in[9];
    float* out = (float*)d_out;

    // workspace layout (total 4.52 MB, unchanged footprint):
    //   partq (f64, 2 MB) + partk (f32, 1 MB): dead after a2
    //   cand (2 MB) aliases partq, born in collect
    //   rmaxpartT (512 KB, [row][block]) in the old wknew slot, born in gemmB
    char* ws = (char*)d_ws;
    double* partq  = (double*)(ws);                        // 2,097,152
    float*  partk  = (float*)(ws + 2097152);               // 1,048,576
    int*    cand   = (int*)(ws);                           // alias partq
    double* outq64 = (double*)(ws + 3145728);              // 262,144
    unsigned short* outq16 = (unsigned short*)(ws + 3145728 + 262144); // 65,536
    int*    ccnt   = (int*)(ws + 3145728 + 262144 + 65536);            // 1,024
    unsigned* rmaxpartT = (unsigned*)(ws + 3145728 + 262144 + 65536 + 2048); // 524,288

    moco_a1<<<dim3(NCHUNK, 128), 256, 0, stream>>>(q, k, Wq, Wk, partq, partk);
    moco_a2<<<dim3(Bsz), 128, 0, stream>>>(partq, partk, outq64, outq16, ccnt, out);
    moco_gemmB<<<dim3(GBLK), 256, 0, stream>>>(outq16, queue, rmaxpartT, out);
    moco_collect<<<dim3(4, Bsz), 512, 0, stream>>>(out, rmaxpartT, cand, ccnt);
    moco_select<<<dim3(Bsz), 512, 0, stream>>>(out, rmaxpartT, cand, ccnt, outq64, queue,
                                               alpha, beta, i1a, i1b, i2, out);
}

// Round 10
// 241.484 us; speedup vs baseline: 1.0782x; 1.0782x over previous
//
#include <hip/hip_runtime.h>
#include <hip/hip_bf16.h>
#include <math.h>

// Problem constants
#define Bsz   256
#define INDIM 2048
#define Dd    128
#define Kq    65536
#define NH    32
#define S1n   16
#define S2n   16
#define ROWLEN (1 + Kq + S1n + S2n)   // 65569
#define CAP   2048                     // survivor cap after fine prune (rank set)
#define CAPL  6144                     // lossless collect window (R2-proven capacity)
#define NCHUNK 8                       // split-K chunks of 256 for encoder GEMM
#define CK    256                      // K per chunk
#define GBLK  512                      // gemmB grid (2 tiles of 64 cols each)

typedef __attribute__((ext_vector_type(8))) short short8;
typedef __attribute__((ext_vector_type(4))) float f32x4;
typedef float float4a __attribute__((ext_vector_type(4), aligned(4)));
union U16x8 { uint4 u4; short8 s8; };

static __device__ inline unsigned short bf16rne(float f) {
    unsigned u = __float_as_uint(f);
    unsigned r = (u + 0x7FFFu + ((u >> 16) & 1u)) >> 16;
    return (unsigned short)r;
}
static __device__ inline unsigned fkey(float f) {   // monotone uint key
    unsigned u = __float_as_uint(f);
    return (u & 0x80000000u) ? ~u : (u | 0x80000000u);
}
static __device__ inline float funkey(unsigned key) {
    unsigned u = (key & 0x80000000u) ? (key & 0x7FFFFFFFu) : ~key;
    return __uint_as_float(u);
}

// ---------------- Kernel A0: form Wk_new = 0.999*Wk + 0.001*Wq (fp32) ----------
// Restored from R8: the R9 inline fusion doubled a1's k-path weight loads for a
// ~5us launch saving — bad trade.
__global__ __launch_bounds__(256) void moco_a0(const float* __restrict__ Wq,
                                               const float* __restrict__ Wk,
                                               float* __restrict__ wknew) {
    int i = blockIdx.x * 256 + threadIdx.x;       // float4 index, 65536 total
    float4 wq = ((const float4*)Wq)[i];
    float4 wk = ((const float4*)Wk)[i];
    float4 wn;
    wn.x = 0.999f * wk.x + 0.001f * wq.x;
    wn.y = 0.999f * wk.y + 0.001f * wq.y;
    wn.z = 0.999f * wk.z + 0.001f * wq.z;
    wn.w = 0.999f * wk.w + 0.001f * wq.w;
    ((float4*)wknew)[i] = wn;
}

// ---------------- Kernel A1: fp64 split-K encoder GEMM (R8-verbatim) -----------
__global__ __launch_bounds__(256) void moco_a1(const float* __restrict__ q,
                                               const float* __restrict__ k,
                                               const float* __restrict__ Wq,
                                               const float* __restrict__ wknew,
                                               double* __restrict__ partq,
                                               float* __restrict__ partk) {
    int kc    = blockIdx.x;        // 0..NCHUNK-1
    int grp   = blockIdx.y;        // 0..127, 4 rows each
    int vrow0 = grp * 4;
    bool isK  = (vrow0 >= Bsz);
    const float* inp = isK ? k : q;
    const float* W   = isK ? wknew : Wq;
    int row0 = isK ? (vrow0 - Bsz) : vrow0;
    int i0 = kc * CK;

    __shared__ float s_in[4 * CK];
    #pragma unroll
    for (int it = 0; it < 4; ++it) {
        int idx = threadIdx.x + it * 256;
        int rr = idx >> 8, ii = idx & (CK - 1);
        s_in[idx] = inp[(size_t)(row0 + rr) * INDIM + i0 + ii];
    }
    __syncthreads();

    int ct = threadIdx.x & 63;     // one wave == one row -> srow reads broadcast
    int rt = threadIdx.x >> 6;
    int d0 = ct * 2;
    const float* baseW = W + (size_t)i0 * Dd + d0;
    const float* srow = &s_in[rt * CK];

    double acc0 = 0, acc1 = 0;
    #pragma unroll 16
    for (int i = 0; i < CK; ++i) {
        float2 w = *(const float2*)(baseW + (size_t)i * Dd);
        double a = (double)srow[i];
        acc0 += a * (double)w.x;
        acc1 += a * (double)w.y;
    }

    int prow = row0 + rt;
    if (isK) {
        float2 r; r.x = (float)acc0; r.y = (float)acc1;
        *(float2*)(partk + ((size_t)kc * 256 + prow) * Dd + d0) = r;
    } else {
        double2 r; r.x = acc0; r.y = acc1;
        *(double2*)(partq + ((size_t)kc * 256 + prow) * Dd + d0) = r;
    }
}

// ---------------- Kernel A2: combine, normalize (f64), pos logit, labels, bf16 out_q ----
__global__ __launch_bounds__(128) void moco_a2(const double* __restrict__ partq,
                                               const float* __restrict__ partk,
                                               double* __restrict__ outq64,
                                               unsigned short* __restrict__ outq16,
                                               int* __restrict__ ccnt,
                                               float* __restrict__ out) {
    int b = blockIdx.x, d = threadIdx.x;
    if (d == 0) ccnt[b] = 0;                     // init for moco_collect
    double sq = 0, sk = 0;
    #pragma unroll
    for (int kc = 0; kc < NCHUNK; ++kc) {
        sq += partq[((size_t)kc * 256 + b) * Dd + d];
        sk += (double)partk[((size_t)kc * 256 + b) * Dd + d];
    }
    __shared__ double red[128];
    red[d] = sq * sq; __syncthreads();
    for (int s = 64; s > 0; s >>= 1) { if (d < s) red[d] += red[d + s]; __syncthreads(); }
    double nq = sqrt(red[0]); __syncthreads();
    red[d] = sk * sk; __syncthreads();
    for (int s = 64; s > 0; s >>= 1) { if (d < s) red[d] += red[d + s]; __syncthreads(); }
    double nk = sqrt(red[0]); __syncthreads();

    double oq = sq / fmax(nq, 1e-12);
    double ok = sk / fmax(nk, 1e-12);
    outq64[(size_t)b * Dd + d] = oq;
    outq16[(size_t)b * Dd + d] = bf16rne((float)oq);

    red[d] = oq * ok; __syncthreads();
    for (int s = 64; s > 0; s >>= 1) { if (d < s) red[d] += red[d + s]; __syncthreads(); }
    if (d == 0) {
        out[(size_t)b * ROWLEN] = (float)(red[0] / 0.07);
        ((int*)out)[(size_t)Bsz * ROWLEN + b] = 0;   // labels
    }
}

// ---------------- Kernel B: bf16 MFMA GEMM + per-row max -> out[:,1:1+K] -------
// rmaxpartT: [row][block] so downstream reads each row's 512 block-maxima as
// one contiguous coalesced 2KB stretch. Scatter store is fire-and-forget.
#define GB_BN 64
__global__ __launch_bounds__(256) void moco_gemmB(const unsigned short* __restrict__ outq16,
                                                  const float* __restrict__ Q,
                                                  unsigned* __restrict__ rmaxpartT,
                                                  float* __restrict__ out) {
    int tid = threadIdx.x;
    int w = tid >> 6, lane = tid & 63;
    int quad = lane >> 4, l16 = lane & 15;
    int bn_base = blockIdx.x * (2 * GB_BN);

    __shared__ unsigned short q_lds[64 * 136];   // stride 136 bf16
    __shared__ unsigned s_rmax[256];
    s_rmax[tid] = 0;

    // A fragments from global bf16 (L2-hot 64 KB), reused across both tiles
    short8 afr[4][4];
    #pragma unroll
    for (int i = 0; i < 4; ++i)
        #pragma unroll
        for (int kc = 0; kc < 4; ++kc) {
            U16x8 u;
            u.u4 = *(const uint4*)(outq16 + (size_t)(w * 64 + i * 16 + l16) * Dd + kc * 32 + quad * 8);
            afr[i][kc] = u.s8;
        }

    // prefetch tile 0 queue rows into registers
    int r0 = tid >> 4, kb = tid & 15;            // 16 rows x 16 col-chunks
    float4 pre[8];
    {
        const float* qb = Q + (size_t)bn_base * Dd + (size_t)kb * 8;
        #pragma unroll
        for (int it = 0; it < 4; ++it) {
            const float4* g = (const float4*)(qb + (size_t)(r0 + it * 16) * Dd);
            pre[2 * it]     = g[0];
            pre[2 * it + 1] = g[1];
        }
    }

    const float invT = (float)(1.0 / 0.07);

    #pragma unroll
    for (int tt = 0; tt < 2; ++tt) {
        int bn0 = bn_base + tt * GB_BN;

        // convert prefetched regs -> LDS (fp32 -> bf16 RNE)
        #pragma unroll
        for (int it = 0; it < 4; ++it) {
            float4 f0 = pre[2 * it], f1 = pre[2 * it + 1];
            uint4 pk;
            pk.x = ((unsigned)bf16rne(f0.y) << 16) | bf16rne(f0.x);
            pk.y = ((unsigned)bf16rne(f0.w) << 16) | bf16rne(f0.z);
            pk.z = ((unsigned)bf16rne(f1.y) << 16) | bf16rne(f1.x);
            pk.w = ((unsigned)bf16rne(f1.w) << 16) | bf16rne(f1.z);
            *(uint4*)&q_lds[(r0 + it * 16) * 136 + kb * 8] = pk;
        }
        __syncthreads();

        // issue tile-1 loads now; they complete under tile-0 MFMA + stores
        if (tt == 0) {
            const float* qb2 = Q + (size_t)(bn_base + GB_BN) * Dd + (size_t)kb * 8;
            #pragma unroll
            for (int it = 0; it < 4; ++it) {
                const float4* g = (const float4*)(qb2 + (size_t)(r0 + it * 16) * Dd);
                pre[2 * it]     = g[0];
                pre[2 * it + 1] = g[1];
            }
        }

        f32x4 acc[4][4];
        #pragma unroll
        for (int i = 0; i < 4; ++i)
            #pragma unroll
            for (int j = 0; j < 4; ++j)
                acc[i][j] = (f32x4){0.f, 0.f, 0.f, 0.f};

        #pragma unroll
        for (int kc = 0; kc < 4; ++kc) {
            short8 bfr[4];
            #pragma unroll
            for (int j = 0; j < 4; ++j)
                bfr[j] = *(const short8*)&q_lds[(j * 16 + l16) * 136 + kc * 32 + quad * 8];
            #pragma unroll
            for (int i = 0; i < 4; ++i)
                #pragma unroll
                for (int j = 0; j < 4; ++j)
                    acc[i][j] = __builtin_amdgcn_mfma_f32_16x16x32_bf16(afr[i][kc], bfr[j], acc[i][j], 0, 0, 0);
        }

        #pragma unroll
        for (int i = 0; i < 4; ++i) {
            int rbase = w * 64 + i * 16 + quad * 4;
            #pragma unroll
            for (int reg = 0; reg < 4; ++reg) {
                size_t ro = (size_t)(rbase + reg) * ROWLEN + 1 + bn0;
                float v0 = acc[i][0][reg] * invT;
                float v1 = acc[i][1][reg] * invT;
                float v2 = acc[i][2][reg] * invT;
                float v3 = acc[i][3][reg] * invT;
                out[ro + l16]      = v0;
                out[ro + 16 + l16] = v1;
                out[ro + 32 + l16] = v2;
                out[ro + 48 + l16] = v3;
                float m = fmaxf(fmaxf(v0, v1), fmaxf(v2, v3));
                atomicMax(&s_rmax[rbase + reg], fkey(m));
            }
        }
        __syncthreads();   // q_lds + s_rmax complete before next tile / final store
    }

    // transposed scatter: row-major layout for coalesced downstream reads
    rmaxpartT[(size_t)tid * GBLK + blockIdx.x] = s_rmax[tid];
}

// ---------------- Kernel C: candidate collection, LOSSLESS to 6144 -------------
// R9 post-mortem: rows with count(vmax-2) in (2048,6144] overflowed the 2048
// cand cap and fell into select's serial full-row repair rescan — a ~60us
// straggler that set select's duration (warm replays identical). Fix: cand
// stores ushort indices (idx < 65536 fits 16 bits) -> capacity 6144/row in the
// same 3MB aliased workspace. LDS stage also 6144. Repair now only for
// count > 6144 or < 32 (R2's validated adaptive regime).
__global__ __launch_bounds__(512) void moco_collect(const float* __restrict__ out,
                                                    const unsigned* __restrict__ rmaxpartT,
                                                    unsigned short* __restrict__ cand,
                                                    int* __restrict__ ccnt) {
    int row = blockIdx.y, chunk = blockIdx.x;
    int t = threadIdx.x;
    __shared__ int s_li[CAPL];                   // 24 KB
    __shared__ unsigned s_mk[512];
    __shared__ int s_cnt, s_base;
    if (t == 0) s_cnt = 0;
    s_mk[t] = rmaxpartT[(size_t)row * GBLK + t];   // coalesced
    __syncthreads();
    for (int s = 256; s > 0; s >>= 1) {
        if (t < s) { unsigned a = s_mk[t], b = s_mk[t + s]; s_mk[t] = a > b ? a : b; }
        __syncthreads();
    }
    float vmax = funkey(s_mk[0]);
    float thresh = vmax - 2.0f;

    const float4a* p4 = (const float4a*)(out + (size_t)row * ROWLEN + 1);
    int base = chunk * 4096 + t;                 // float4 index, stride 512
    float4a v0 = p4[base];
    float4a v1 = p4[base + 512];
    float4a v2 = p4[base + 1024];
    float4a v3 = p4[base + 1536];
    float4a v4 = p4[base + 2048];
    float4a v5 = p4[base + 2560];
    float4a v6 = p4[base + 3072];
    float4a v7 = p4[base + 3584];

#define CCHK(vv, ii)                                                                       \
    {                                                                                      \
        _Pragma("unroll")                                                                  \
        for (int e = 0; e < 4; ++e) {                                                      \
            if (vv[e] >= thresh) {                                                         \
                int p = atomicAdd(&s_cnt, 1);                                              \
                if (p < CAPL) s_li[p] = (base + (ii) * 512) * 4 + e;                       \
            }                                                                              \
        }                                                                                  \
    }
    CCHK(v0, 0) CCHK(v1, 1) CCHK(v2, 2) CCHK(v3, 3)
    CCHK(v4, 4) CCHK(v5, 5) CCHK(v6, 6) CCHK(v7, 7)
#undef CCHK

    __syncthreads();
    if (t == 0) s_base = atomicAdd(&ccnt[row], s_cnt);   // ONE device atomic per block
    __syncthreads();
    int cnt = s_cnt < CAPL ? s_cnt : CAPL;
    int b0 = s_base;
    for (int i = t; i < cnt; i += 512) {
        int pos = b0 + i;
        if (pos < CAPL) cand[(size_t)row * CAPL + pos] = (unsigned short)s_li[i];
    }
}

// ---------------- Kernel D: fused prune + fp64 re-rank + mixed logits ----------
// Fast path now covers n0 in [NH, 6144] (no straggler rescan). Prune semantics
// R2/R8-verbatim: 128-bin histogram over [vmax-W, vmax], rank-NH bin minus
// 0.25-logit margin, trim to <= CAP survivors; exact f64 re-rank; mixed logits.
__global__ __launch_bounds__(512) void moco_select(const float* __restrict__ outv,
                                                   const unsigned* __restrict__ rmaxpartT,
                                                   const unsigned short* __restrict__ cand,
                                                   const int* __restrict__ ccnt,
                                                   const double* __restrict__ outq64,
                                                   const float* __restrict__ Qm,
                                                   const float* __restrict__ alpha,
                                                   const float* __restrict__ beta,
                                                   const int* __restrict__ i1a,
                                                   const int* __restrict__ i1b,
                                                   const int* __restrict__ i2,
                                                   float* __restrict__ out) {
    int row = blockIdx.x;
    int t = threadIdx.x;
    const float* p = outv + (size_t)row * ROWLEN + 1;
    __shared__ float lv[CAPL];
    __shared__ int   li[CAPL];
    __shared__ double dval[CAP];
    __shared__ int    didx[CAP];
    __shared__ double oq[Dd];
    __shared__ unsigned hist[128];
    __shared__ unsigned s_mk[512];
    __shared__ int s_cnt, s_thr;
    __shared__ int hard[NH];

    for (int i = t; i < Dd; i += 512) oq[i] = outq64[(size_t)row * Dd + i];
    if (t < NH) hard[t] = 0;                     // defensive init
    s_mk[t] = rmaxpartT[(size_t)row * GBLK + t]; // coalesced
    __syncthreads();
    for (int s = 256; s > 0; s >>= 1) {
        if (t < s) { unsigned a = s_mk[t], b = s_mk[t + s]; s_mk[t] = a > b ? a : b; }
        __syncthreads();
    }
    float vmax = funkey(s_mk[0]);

    // ---- prune phase ----
    int n0 = ccnt[row];
    float W = 2.0f;
    int cnt;
    if (n0 >= NH && n0 <= CAPL) {
        cnt = n0;
        for (int c = t; c < cnt; c += 512) {
            int idx = (int)cand[(size_t)row * CAPL + c];   // ushort: inherently < Kq
            li[c] = idx;
            lv[c] = p[idx];
        }
        __syncthreads();
    } else {
        // repair path (count > 6144 or < 32): adaptive full scan, R2-verbatim
        const float4a* p4 = (const float4a*)p;
        cnt = 0;
        for (int attempt = 0; attempt < 5; ++attempt) {
            if (t == 0) s_cnt = 0;
            __syncthreads();
            float thresh = vmax - W;
            #pragma unroll 8
            for (int it = 0; it < 32; ++it) {
                int vi = t + it * 512;              // < 16384
                float4a v = p4[vi];
                #pragma unroll
                for (int e = 0; e < 4; ++e) {
                    float f = v[e];
                    if (f >= thresh) {
                        int pos = atomicAdd(&s_cnt, 1);
                        if (pos < CAPL) { lv[pos] = f; li[pos] = vi * 4 + e; }
                    }
                }
            }
            __syncthreads();
            cnt = s_cnt;
            if (cnt >= NH && cnt <= CAPL) break;
            W = (cnt > CAPL) ? W * 0.5f : W * 2.0f;
            __syncthreads();
        }
        if (cnt > CAPL) cnt = CAPL;   // pathological safety
    }

    // fine prune: 128-bin histogram over [vmax-W, vmax], rank-NH bin minus margin
    if (t < 128) hist[t] = 0;
    __syncthreads();
    float lo = vmax - W;
    float scale = 128.0f / W;
    for (int c = t; c < cnt; c += 512) {
        int b = (int)((lv[c] - lo) * scale);
        b = b < 0 ? 0 : (b > 127 ? 127 : b);
        atomicAdd(&hist[b], 1u);
    }
    __syncthreads();
    if (t == 0) {
        unsigned cum = 0; int b = 127;
        for (; b > 0; --b) { cum += hist[b]; if (cum >= NH) break; }
        int mb = (int)(0.25f * scale) + 1;     // 0.25 logit-unit safety margin
        b -= mb; if (b < 0) b = 0;
        long total = 0;
        for (int x = 127; x >= b; --x) total += hist[x];
        while (total > CAP && b < 127) { total -= hist[b]; ++b; }
        s_thr = b;
        s_cnt = 0;
    }
    __syncthreads();
    float thresh2 = lo + (float)s_thr * (W / 128.0f);
    for (int c = t; c < cnt; c += 512) {
        if (lv[c] >= thresh2) {
            int pos = atomicAdd(&s_cnt, 1);
            if (pos < CAP) didx[pos] = li[c];   // survivors straight to LDS
        }
    }
    __syncthreads();
    int n = s_cnt < CAP ? s_cnt : CAP;
    if (n < 1) n = 1;

    // ---- finalize phase (R8-verbatim semantics, stride 512) ----
    for (int c = t; c < n; c += 512) {
        int idx = didx[c];
        const float* qr = Qm + (size_t)idx * Dd;
        double dot = 0;
        #pragma unroll 4
        for (int i = 0; i < Dd; ++i) dot += oq[i] * (double)qr[i];
        dval[c] = dot / 0.07;
    }
    __syncthreads();

    // exact rank (ties -> lower index first, matching lax.top_k)
    for (int c = t; c < n; c += 512) {
        double v = dval[c]; int id = didx[c];
        int r = 0;
        for (int j = 0; j < n; ++j) {
            double vj = dval[j];
            r += (vj > v) || (vj == v && didx[j] < id);
        }
        if (r < NH) hard[r] = id;
    }
    __syncthreads();

    if (t < S1n) {
        double a = (double)alpha[(size_t)row * S1n + t];
        int g1 = hard[i1a[(size_t)row * S1n + t] & (NH - 1)];
        int g2 = hard[i1b[(size_t)row * S1n + t] & (NH - 1)];
        const float* q1 = Qm + (size_t)g1 * Dd;
        const float* q2 = Qm + (size_t)g2 * Dd;
        double nn = 0, qd = 0;
        #pragma unroll 4
        for (int i = 0; i < Dd; ++i) {
            double m = a * (double)q1[i] + (1.0 - a) * (double)q2[i];
            nn += m * m; qd += oq[i] * m;
        }
        double logit = qd / fmax(sqrt(nn), 1e-12) / 0.07;
        out[(size_t)row * ROWLEN + 1 + Kq + t] = (float)logit;
    } else if (t < S1n + S2n) {
        int s = t - S1n;
        double bb = (double)beta[(size_t)row * S2n + s] * 0.5;
        int g = hard[i2[(size_t)row * S2n + s] & (NH - 1)];
        const float* qg = Qm + (size_t)g * Dd;
        double nn = 0, qd = 0;
        #pragma unroll 4
        for (int i = 0; i < Dd; ++i) {
            double m = bb * oq[i] + (1.0 - bb) * (double)qg[i];
            nn += m * m; qd += oq[i] * m;
        }
        double logit = qd / fmax(sqrt(nn), 1e-12) / 0.07;
        out[(size_t)row * ROWLEN + 1 + Kq + S1n + s] = (float)logit;
    }
}

extern "C" void kernel_launch(void* const* d_in, const int* in_sizes, int n_in,
                              void* d_out, int out_size, void* d_ws, size_t ws_size,
                              hipStream_t stream) {
    const float* q     = (const float*)d_in[0];
    const float* k     = (const float*)d_in[1];
    const float* Wq    = (const float*)d_in[2];
    const float* Wk    = (const float*)d_in[3];
    const float* queue = (const float*)d_in[4];
    const float* alpha = (const float*)d_in[5];
    const float* beta  = (const float*)d_in[6];
    const int*   i1a   = (const int*)d_in[7];
    const int*   i1b   = (const int*)d_in[8];
    const int*   i2    = (const int*)d_in[9];
    float* out = (float*)d_out;

    // workspace layout (total 4.52 MB, unchanged footprint):
    //   partq (f64, 2 MB) + partk (f32, 1 MB): dead after a2
    //   cand (ushort, 256x6144 = 3 MB) aliases [partq|partk], born in collect
    //   wknew (1 MB): dead after a1; rmaxpartT (512 KB) aliases it, born in gemmB
    char* ws = (char*)d_ws;
    double* partq  = (double*)(ws);                        // 2,097,152
    float*  partk  = (float*)(ws + 2097152);               // 1,048,576
    unsigned short* cand = (unsigned short*)(ws);          // 3,145,728 (alias partq+partk)
    double* outq64 = (double*)(ws + 3145728);              // 262,144
    unsigned short* outq16 = (unsigned short*)(ws + 3145728 + 262144); // 65,536
    int*    ccnt   = (int*)(ws + 3145728 + 262144 + 65536);            // 1,024
    float* wknew   = (float*)(ws + 3145728 + 262144 + 65536 + 2048);   // 1,048,576
    unsigned* rmaxpartT = (unsigned*)wknew;                 // alias, 256*512*4 = 524,288

    moco_a0<<<dim3(256), 256, 0, stream>>>(Wq, Wk, wknew);
    moco_a1<<<dim3(NCHUNK, 128), 256, 0, stream>>>(q, k, Wq, wknew, partq, partk);
    moco_a2<<<dim3(Bsz), 128, 0, stream>>>(partq, partk, outq64, outq16, ccnt, out);
    moco_gemmB<<<dim3(GBLK), 256, 0, stream>>>(outq16, queue, rmaxpartT, out);
    moco_collect<<<dim3(4, Bsz), 512, 0, stream>>>(out, rmaxpartT, cand, ccnt);
    moco_select<<<dim3(Bsz), 512, 0, stream>>>(out, rmaxpartT, cand, ccnt, outq64, queue,
                                               alpha, beta, i1a, i1b, i2, out);
}